// Round 5
// baseline (92.825 us; speedup 1.0000x reference)
//
#include <hip/hip_runtime.h>
#include <hip/hip_bf16.h>
#include <float.h>

#define BB 128
#define SS 4096
#define TT 48
#define EE 10
#define NBLK 512          // 4 blocks per batch row; all co-resident (see launch_bounds)
#define TPW 25            // tokens per wave in phase V: 2048 waves * 25 >= 50257

__device__ __forceinline__ int rfl(int x) { return __builtin_amdgcn_readfirstlane(x); }

// ---------------------------------------------------------------------------
// ws layout:
//   [0      .. 4    )  unsigned ctr          (memset to 0 each call -> node 1)
//   [64     .. 65600)  unsigned char safe[vocab]
//   [65600  .. 66112)  int flags[128]        (cleared by block 0, phase V)
//   [66112  .. 66624)  int row_done[128]     (cleared by block 0, phase V)
//   [131072 .. +25MB)  fallback backpointers (touched only on fallback)
//
// rowC[i] = max_j(trans[i][j] - trans[0][j]) + 1e-3 is state-independent: for
// ANY state x, (forall i>=1: x_i + rowC[i] <= x_0) => Viterbi argmax row out
// of x is all-O, margin absorbing f32 rounding. Spurious failure only flags
// the row -> exact fallback, never wrongness.
//
// Device barrier: each block releases (threadfence + atomicAdd ctr), tid 0
// acquire-spins until ctr == NBLK. __launch_bounds__(256,2) caps VGPR at 128
// -> >=2 blocks/CU -> all 512 blocks co-resident -> no deadlock possible.
// ---------------------------------------------------------------------------
__global__ __launch_bounds__(256, 2) void k_all(
    const int* __restrict__ tok_ids, const float* __restrict__ emb,
    const float* __restrict__ W, const float* __restrict__ bias,
    const float* __restrict__ start_t, const float* __restrict__ end_t,
    const float* __restrict__ trans, int* __restrict__ out,
    unsigned* __restrict__ ctr, unsigned char* __restrict__ safe,
    int* __restrict__ flags, int* __restrict__ row_done,
    unsigned char* __restrict__ bp_all, int vocab)
{
  __shared__ float rowC[TT];
  __shared__ int s_run;
  const int tid = threadIdx.x;
  const int lane = tid & 63;
  const int wv = tid >> 6;
  const int bid = blockIdx.x;

  // rowC (every block; trans is L1/L2-resident 9KB)
  if (tid < TT) {
    float acc = -FLT_MAX;
#pragma unroll 1
    for (int j = 0; j < TT; ++j) acc = fmaxf(acc, trans[tid * TT + j] - trans[j]);
    rowC[tid] = acc + 1e-3f;
  }
  if (bid == 0 && tid < BB) { flags[tid] = 0; row_done[tid] = 0; }
  __syncthreads();

  const int jj = lane < TT ? lane : TT - 1;
  const float rc = rowC[jj];
  float w[EE];
#pragma unroll
  for (int d = 0; d < EE; ++d) w[d] = W[jj * EE + d];
  const float base_mix = bias[jj] + trans[jj];   // bias + trans[0][j]

  // ---- phase V: safe[] table, 25 wave-uniform tokens per wave ----
  const int tok0 = rfl(bid * 4 + wv) * TPW;
#pragma unroll 5
  for (int k = 0; k < TPW; ++k) {
    const int tok = tok0 + k;
    if (tok < vocab) {
      const float* er = emb + (size_t)tok * EE;
      float x = base_mix;
#pragma unroll
      for (int d = 0; d < EE; ++d) x = fmaf(er[d], w[d], x);
      const float x0 = __shfl(x, 0, 64);
      const bool ok = (lane == 0 || lane >= TT) ? true : (x + rc <= x0);
      const int s = __all(ok) ? 1 : 0;
      if (lane == 0) safe[tok] = (unsigned char)s;
    }
  }

  // ---- device barrier ----
  __syncthreads();
  if (tid == 0) {
    __threadfence();                 // release: safe[] + clears
    atomicAdd(ctr, 1u);
    while (__hip_atomic_load(ctr, __ATOMIC_ACQUIRE, __HIP_MEMORY_SCOPE_AGENT)
           < (unsigned)NBLK) {
      __builtin_amdgcn_s_sleep(2);
    }
    __threadfence();                 // acquire: invalidate L1 for this CU
  }
  __syncthreads();

  // ---- phase B: this block's row chunk ----
  const int b = bid >> 2, chunk = bid & 3;
  const int p0 = chunk * 1024 + tid * 4;
  const int4 tk = *(const int4*)(tok_ids + b * SS + p0);
  int fail = 0;
  if (p0 != 0)          fail |= !safe[tk.x];    // t=0 handled exactly below
  fail |= !safe[tk.y];
  fail |= !safe[tk.z];
  if (p0 + 3 != SS - 1) fail |= !safe[tk.w];    // S-1 has no outgoing check
  if (fail) atomicOr(&flags[b], 1);

  int wtag = 0;
  if (chunk == 0 && tid < 64) {
    // exact t=0 check: state uses start bias; rowC test is state-independent
    const int tkA = tok_ids[b * SS];
    const float* er = emb + (size_t)tkA * EE;
    float x = bias[jj] + start_t[jj];
#pragma unroll
    for (int d = 0; d < EE; ++d) x = fmaf(er[d], w[d], x);
    const float x0 = __shfl(x, 0, 64);
    const bool ok = (lane == 0 || lane >= TT) ? true : (x + rc <= x0);
    if (!__all(ok) && lane == 0) atomicOr(&flags[b], 1);
  }
  if (chunk == 3 && tid >= 192) {
    // final tag = argmax_j( em + b + trans[0][j] + end[j] ), ties -> lowest j
    const int tkL = tok_ids[b * SS + SS - 1];
    const float* er = emb + (size_t)tkL * EE;
    float y = base_mix + end_t[jj];
#pragma unroll
    for (int d = 0; d < EE; ++d) y = fmaf(er[d], w[d], y);
    if (lane >= TT) y = -FLT_MAX;
    int idx = lane;
#pragma unroll
    for (int m = 32; m; m >>= 1) {
      const float oy = __shfl_xor(y, m, 64);
      const int oi = __shfl_xor(idx, m, 64);
      if (oy > y || (oy == y && oi < idx)) { y = oy; idx = oi; }
    }
    wtag = idx;
  }
  int4 z = make_int4(0, 0, 0, 0);
  if (chunk == 3 && tid == 255) z.w = wtag;
  *(int4*)(out + b * SS + p0) = z;

  // ---- row completion: 4th finisher runs fallback if row flagged ----
  __syncthreads();
  if (tid == 0) {
    __threadfence();                              // release this block's stores
    const int old = atomicAdd(&row_done[b], 1);
    int go = 0;
    if (old == 3) {
      __threadfence();                            // acquire other blocks' work
      go = atomicOr(&flags[b], 0);                // atomic read of final flag
    }
    s_run = go;
  }
  __syncthreads();
  if (s_run == 0) return;

  // ---- exact sequential fallback (reference semantics), wave 0 only ----
  if (tid >= 64) return;
  unsigned char* __restrict__ bp = bp_all + (size_t)b * (SS - 1) * TT;
  float sc;
  {
    const int tkq = tok_ids[b * SS];
    const float* er = emb + (size_t)tkq * EE;
    float em = bias[jj];
#pragma unroll
    for (int d = 0; d < EE; ++d) em = fmaf(er[d], w[d], em);
    sc = start_t[jj] + em;
  }
  for (int t = 1; t < SS; ++t) {
    const int tkq = tok_ids[b * SS + t];
    const float* er = emb + (size_t)tkq * EE;
    float em = bias[jj];
#pragma unroll
    for (int d = 0; d < EE; ++d) em = fmaf(er[d], w[d], em);
    float best = -FLT_MAX; int bpi = 0;
#pragma unroll 1
    for (int i = 0; i < TT; ++i) {
      const float v = (__shfl(sc, i, 64) + trans[i * TT + jj]) + em;
      if (v > best) { best = v; bpi = i; }
    }
    if (lane < TT) bp[(size_t)(t - 1) * TT + lane] = (unsigned char)bpi;
    sc = best;
  }
  {
    float y = sc + end_t[jj];
    if (lane >= TT) y = -FLT_MAX;
    int idx = lane;
#pragma unroll
    for (int m = 32; m; m >>= 1) {
      const float oy = __shfl_xor(y, m, 64);
      const int oi = __shfl_xor(idx, m, 64);
      if (oy > y || (oy == y && oi < idx)) { y = oy; idx = oi; }
    }
    if (lane == 0) {
      int curtag = idx;
      out[b * SS + (SS - 1)] = curtag;
      for (int t = SS - 2; t >= 0; --t) {
        curtag = bp[(size_t)t * TT + curtag];
        out[b * SS + t] = curtag;
      }
    }
  }
}

extern "C" void kernel_launch(void* const* d_in, const int* in_sizes, int n_in,
                              void* d_out, int out_size, void* d_ws, size_t ws_size,
                              hipStream_t stream) {
  const int*   tok_ids = (const int*)d_in[0];
  const float* emb     = (const float*)d_in[1];
  const float* W       = (const float*)d_in[2];
  const float* bias    = (const float*)d_in[3];
  const float* start_t = (const float*)d_in[4];
  const float* end_t   = (const float*)d_in[5];
  const float* trans   = (const float*)d_in[6];
  int* out = (int*)d_out;

  const int vocab = in_sizes[1] / EE;
  unsigned*      ctr      = (unsigned*)d_ws;
  unsigned char* safe     = (unsigned char*)d_ws + 64;
  int*           flags    = (int*)((char*)d_ws + 65600);
  int*           row_done = (int*)((char*)d_ws + 66112);
  unsigned char* bp       = (unsigned char*)d_ws + 131072;

  hipMemsetAsync(ctr, 0, 4, stream);   // barrier counter reset (node 1)
  k_all<<<NBLK, 256, 0, stream>>>(tok_ids, emb, W, bias, start_t, end_t, trans,
                                  out, ctr, safe, flags, row_done, bp, vocab);
}

// Round 6
// 36.380 us; speedup vs baseline: 2.5515x; 2.5515x over previous
//
#include <hip/hip_runtime.h>
#include <hip/hip_bf16.h>
#include <float.h>

#define BB 128
#define SS 4096
#define TT 48
#define EE 10

// ---------------------------------------------------------------------------
// ws layout:
//   [0      .. 65536)  unsigned char safe[vocab]
//   [65536  .. +512 )  int flags[128]     (cleared by k_safe block 0)
//   [66048  .. +512 )  int row_done[128]  (cleared by k_safe block 0)
//   [131072 .. +25MB)  fallback backpointers (touched only on fallback)
//
// rowC[i] = max_j(trans[i][j] - trans[0][j]) + 1e-3 is state-independent: for
// ANY state x, (forall i>=1: x_i + rowC[i] <= x_0) => the Viterbi argmax row
// out of x is all-O (tag 0), margin absorbing f32 rounding. A spurious
// failure only flags the row -> exact fallback, never wrongness.
// ---------------------------------------------------------------------------

// Node 1: one THREAD per token. W + folded constants staged in LDS
// (uniform-address broadcast reads). safe[tok] = 1 iff canonical state is
// all-O-dominated.
__global__ __launch_bounds__(256) void k_safe(
    const float* __restrict__ emb, const float* __restrict__ W,
    const float* __restrict__ bias, const float* __restrict__ trans,
    unsigned char* __restrict__ safe, int* __restrict__ flags,
    int* __restrict__ row_done, int vocab)
{
  // sW[i][0..9] = W row i; sW[i][10] = base_i + rowC_i (i>=1) or base_0 (i==0)
  __shared__ float sW[TT][12];
  const int tid = threadIdx.x;

  for (int idx = tid; idx < TT * EE; idx += 256) sW[idx / EE][idx % EE] = W[idx];
  if (tid < TT) {
    const float base = bias[tid] + trans[tid];       // bias_i + trans[0][i]
    if (tid == 0) {
      sW[0][10] = base;
    } else {
      float acc = -FLT_MAX;
#pragma unroll 1
      for (int j = 0; j < TT; ++j) acc = fmaxf(acc, trans[tid * TT + j] - trans[j]);
      sW[tid][10] = base + acc + 1e-3f;              // base_i + rowC_i
    }
    sW[tid][11] = 0.0f;
  }
  if (blockIdx.x == 0 && tid < BB) { flags[tid] = 0; row_done[tid] = 0; }
  __syncthreads();

  const int tok = blockIdx.x * 256 + tid;
  if (tok >= vocab) return;

  // emb row: 40 B, 8-byte aligned -> five float2 loads
  const float2* er = (const float2*)(emb + (size_t)tok * EE);
  const float2 e01 = er[0], e23 = er[1], e45 = er[2], e67 = er[3], e89 = er[4];

  float x0;
  {
    const float4* r = (const float4*)sW[0];
    const float4 a = r[0], bq = r[1], c = r[2];
    float x = c.z;
    x = fmaf(e01.x, a.x, x); x = fmaf(e01.y, a.y, x);
    x = fmaf(e23.x, a.z, x); x = fmaf(e23.y, a.w, x);
    x = fmaf(e45.x, bq.x, x); x = fmaf(e45.y, bq.y, x);
    x = fmaf(e67.x, bq.z, x); x = fmaf(e67.y, bq.w, x);
    x = fmaf(e89.x, c.x, x); x = fmaf(e89.y, c.y, x);
    x0 = x;
  }
  int ok = 1;
#pragma unroll 8
  for (int i = 1; i < TT; ++i) {
    const float4* r = (const float4*)sW[i];
    const float4 a = r[0], bq = r[1], c = r[2];
    float x = c.z;                                    // base_i + rowC_i
    x = fmaf(e01.x, a.x, x); x = fmaf(e01.y, a.y, x);
    x = fmaf(e23.x, a.z, x); x = fmaf(e23.y, a.w, x);
    x = fmaf(e45.x, bq.x, x); x = fmaf(e45.y, bq.y, x);
    x = fmaf(e67.x, bq.z, x); x = fmaf(e67.y, bq.w, x);
    x = fmaf(e89.x, c.x, x); x = fmaf(e89.y, c.y, x);
    ok &= (x <= x0);
  }
  safe[tok] = (unsigned char)ok;
}

// Node 2: 4 blocks per row. Zero-fill + safe-gather + t=0 check (chunk 0) +
// final tag (chunk 3); per-row completion counter; the 4th-finishing block
// runs the exact sequential fallback if the row is flagged.
__global__ __launch_bounds__(256) void k_body(
    const int* __restrict__ tok_ids, const float* __restrict__ emb,
    const float* __restrict__ W, const float* __restrict__ bias,
    const float* __restrict__ start_t, const float* __restrict__ end_t,
    const float* __restrict__ trans, const unsigned char* __restrict__ safe,
    int* __restrict__ out, int* __restrict__ flags, int* __restrict__ row_done,
    unsigned char* __restrict__ bp_all)
{
  __shared__ int s_run;
  const int bid = blockIdx.x;
  const int b = bid >> 2, chunk = bid & 3;
  const int tid = threadIdx.x;
  const int lane = tid & 63;
  const int jj = lane < TT ? lane : TT - 1;
  const int p0 = chunk * 1024 + tid * 4;

  const int4 tk = *(const int4*)(tok_ids + b * SS + p0);
  int fail = 0;
  if (p0 != 0)          fail |= !safe[tk.x];     // t=0 handled exactly below
  fail |= !safe[tk.y];
  fail |= !safe[tk.z];
  if (p0 + 3 != SS - 1) fail |= !safe[tk.w];     // S-1 has no outgoing check
  if (fail) atomicOr(&flags[b], 1);

  int wtag = 0;
  if (chunk == 0 && tid < 64) {
    // exact t=0 check: state uses start bias; per-lane rowC from trans (L1)
    float rc = 0.0f;
    if (lane >= 1 && lane < TT) {
      float acc = -FLT_MAX;
#pragma unroll 1
      for (int j = 0; j < TT; ++j) acc = fmaxf(acc, trans[lane * TT + j] - trans[j]);
      rc = acc + 1e-3f;
    }
    const int tkA = tok_ids[b * SS];
    const float* er = emb + (size_t)tkA * EE;
    float x = bias[jj] + start_t[jj];
#pragma unroll
    for (int d = 0; d < EE; ++d) x = fmaf(er[d], W[jj * EE + d], x);
    const float x0 = __shfl(x, 0, 64);
    const bool okl = (lane == 0 || lane >= TT) ? true : (x + rc <= x0);
    if (!__all(okl) && lane == 0) atomicOr(&flags[b], 1);
  }
  if (chunk == 3 && tid >= 192) {
    // final tag = argmax_j( em + b + trans[0][j] + end[j] ), ties -> lowest j
    const int tkL = tok_ids[b * SS + SS - 1];
    const float* er = emb + (size_t)tkL * EE;
    float y = bias[jj] + trans[jj] + end_t[jj];
#pragma unroll
    for (int d = 0; d < EE; ++d) y = fmaf(er[d], W[jj * EE + d], y);
    if (lane >= TT) y = -FLT_MAX;
    int idx = lane;
#pragma unroll
    for (int m = 32; m; m >>= 1) {
      const float oy = __shfl_xor(y, m, 64);
      const int oi = __shfl_xor(idx, m, 64);
      if (oy > y || (oy == y && oi < idx)) { y = oy; idx = oi; }
    }
    wtag = idx;
  }
  int4 z = make_int4(0, 0, 0, 0);
  if (chunk == 3 && tid == 255) z.w = wtag;
  *(int4*)(out + b * SS + p0) = z;

  // ---- row completion: 4th finisher runs fallback if row flagged ----
  __syncthreads();
  if (tid == 0) {
    __threadfence();                           // release this block's stores
    const int old = atomicAdd(&row_done[b], 1);
    int go = 0;
    if (old == 3) {
      __threadfence();                         // acquire other blocks' stores
      go = atomicOr(&flags[b], 0);             // atomic read of final flag
    }
    s_run = go;
  }
  __syncthreads();
  if (s_run == 0) return;

  // ---- exact sequential fallback (reference semantics), wave 0 only ----
  if (tid >= 64) return;
  unsigned char* __restrict__ bp = bp_all + (size_t)b * (SS - 1) * TT;
  float w[EE];
#pragma unroll
  for (int d = 0; d < EE; ++d) w[d] = W[jj * EE + d];
  const float bj = bias[jj];
  float sc;
  {
    const int tkq = tok_ids[b * SS];
    const float* er = emb + (size_t)tkq * EE;
    float em = bj;
#pragma unroll
    for (int d = 0; d < EE; ++d) em = fmaf(er[d], w[d], em);
    sc = start_t[jj] + em;
  }
  for (int t = 1; t < SS; ++t) {
    const int tkq = tok_ids[b * SS + t];
    const float* er = emb + (size_t)tkq * EE;
    float em = bj;
#pragma unroll
    for (int d = 0; d < EE; ++d) em = fmaf(er[d], w[d], em);
    float best = -FLT_MAX; int bpi = 0;
#pragma unroll 1
    for (int i = 0; i < TT; ++i) {
      const float v = (__shfl(sc, i, 64) + trans[i * TT + jj]) + em;
      if (v > best) { best = v; bpi = i; }
    }
    if (lane < TT) bp[(size_t)(t - 1) * TT + lane] = (unsigned char)bpi;
    sc = best;
  }
  {
    float y = sc + end_t[jj];
    if (lane >= TT) y = -FLT_MAX;
    int idx = lane;
#pragma unroll
    for (int m = 32; m; m >>= 1) {
      const float oy = __shfl_xor(y, m, 64);
      const int oi = __shfl_xor(idx, m, 64);
      if (oy > y || (oy == y && oi < idx)) { y = oy; idx = oi; }
    }
    if (lane == 0) {
      int curtag = idx;
      out[b * SS + (SS - 1)] = curtag;
      for (int t = SS - 2; t >= 0; --t) {
        curtag = bp[(size_t)t * TT + curtag];
        out[b * SS + t] = curtag;
      }
    }
  }
}

extern "C" void kernel_launch(void* const* d_in, const int* in_sizes, int n_in,
                              void* d_out, int out_size, void* d_ws, size_t ws_size,
                              hipStream_t stream) {
  const int*   tok_ids = (const int*)d_in[0];
  const float* emb     = (const float*)d_in[1];
  const float* W       = (const float*)d_in[2];
  const float* bias    = (const float*)d_in[3];
  const float* start_t = (const float*)d_in[4];
  const float* end_t   = (const float*)d_in[5];
  const float* trans   = (const float*)d_in[6];
  int* out = (int*)d_out;

  const int vocab = in_sizes[1] / EE;
  unsigned char* safe     = (unsigned char*)d_ws;
  int*           flags    = (int*)((char*)d_ws + 65536);
  int*           row_done = (int*)((char*)d_ws + 66048);
  unsigned char* bp       = (unsigned char*)d_ws + 131072;

  k_safe<<<(vocab + 255) / 256, 256, 0, stream>>>(emb, W, bias, trans, safe,
                                                  flags, row_done, vocab);
  k_body<<<BB * 4, 256, 0, stream>>>(tok_ids, emb, W, bias, start_t, end_t,
                                     trans, safe, out, flags, row_done, bp);
}

// Round 7
// 23.257 us; speedup vs baseline: 3.9912x; 1.5642x over previous
//
#include <hip/hip_runtime.h>
#include <hip/hip_bf16.h>
#include <float.h>

#define BB 128
#define SS 4096
#define TT 48
#define EE 10
#define TPW 4   // tokens per wave in k_vocab

__device__ __forceinline__ int rfl(int x) { return __builtin_amdgcn_readfirstlane(x); }

// ---------------------------------------------------------------------------
// ws layout:
//   [0      .. 65536)  unsigned char safe[vocab]
//   [131072 .. +25MB)  fallback backpointers (touched only on fallback)
//
// rowC[i] = max_j(trans[i][j] - trans[0][j]) + 1e-3 is state-independent: for
// ANY state x, (forall i>=1: x_i + rowC[i] <= x_0) => the Viterbi argmax row
// out of x is all-O (tag 0), margin absorbing f32 rounding. Induction over
// steps: if every step's argmax row is all-O, scores stay x_t + const, so the
// per-token test is an exact validity certificate. Spurious failure only
// triggers the exact fallback, never wrongness.
// ---------------------------------------------------------------------------

// Node 1 (R4's measured-good config): 16 tokens per 256-thread block, 4 per
// wave, wave-uniform token -> scalar emb loads. rowC per block in LDS; the
// serial rowC chain hides under 3142 blocks oversubscribing the CUs.
__global__ __launch_bounds__(256) void k_vocab(
    const float* __restrict__ emb, const float* __restrict__ W,
    const float* __restrict__ bias, const float* __restrict__ trans,
    unsigned char* __restrict__ safe, int vocab)
{
  __shared__ float rowC[TT];
  const int tid = threadIdx.x;
  const int lane = tid & 63;
  const int wv = tid >> 6;

  if (tid < TT) {
    float acc = -FLT_MAX;
#pragma unroll 1
    for (int j = 0; j < TT; ++j) acc = fmaxf(acc, trans[tid * TT + j] - trans[j]);
    rowC[tid] = acc + 1e-3f;
  }
  __syncthreads();

  const int jj = lane < TT ? lane : TT - 1;
  const float rc = rowC[jj];
  float w[EE];
#pragma unroll
  for (int d = 0; d < EE; ++d) w[d] = W[jj * EE + d];
  const float base = bias[jj] + trans[jj];   // bias_j + trans[0][j]

  const int tok0 = rfl(blockIdx.x * (4 * TPW) + wv * TPW);
#pragma unroll
  for (int k = 0; k < TPW; ++k) {
    const int tok = tok0 + k;                // wave-uniform
    if (tok < vocab) {
      const float* er = emb + (size_t)tok * EE;  // uniform -> scalar loads
      float x = base;
#pragma unroll
      for (int d = 0; d < EE; ++d) x = fmaf(er[d], w[d], x);
      const float x0 = __shfl(x, 0, 64);
      const bool ok = (lane == 0 || lane >= TT) ? true : (x + rc <= x0);
      const int s = __all(ok) ? 1 : 0;
      if (lane == 0) safe[tok] = (unsigned char)s;
    }
  }
}

// Node 2: ONE block per batch row, 1024 threads (16 waves), one int4 each.
// Row verdict in an LDS flag -> no device-scope fences/atomics anywhere.
// wave 0: exact t=0 check (start bias). wave 15: final tag, fused into
// thread 1023's zero-store. Fallback (exact sequential Viterbi) behind the
// LDS flag, wave 0 only — never taken on this data.
__global__ __launch_bounds__(1024) void k_row(
    const int* __restrict__ tok_ids, const float* __restrict__ emb,
    const float* __restrict__ W, const float* __restrict__ bias,
    const float* __restrict__ start_t, const float* __restrict__ end_t,
    const float* __restrict__ trans, const unsigned char* __restrict__ safe,
    int* __restrict__ out, unsigned char* __restrict__ bp_all)
{
  __shared__ int s_fail;
  const int b = blockIdx.x;
  const int tid = threadIdx.x;
  const int lane = tid & 63;
  const int jj = lane < TT ? lane : TT - 1;
  const int p0 = tid * 4;

  if (tid == 0) s_fail = 0;
  __syncthreads();

  // ---- gather: 4 positions per thread ----
  const int4 tk = *(const int4*)(tok_ids + b * SS + p0);
  int fail = 0;
  if (p0 != 0)          fail |= !safe[tk.x];     // t=0 handled exactly below
  fail |= !safe[tk.y];
  fail |= !safe[tk.z];
  if (p0 + 3 != SS - 1) fail |= !safe[tk.w];     // S-1 has no outgoing check
  if (fail) atomicOr(&s_fail, 1);                // LDS atomic

  int wtag = 0;
  if (tid < 64) {
    // exact t=0 check: state uses start bias; per-lane rowC inline (trans L1)
    float rc = 0.0f;
    if (lane >= 1 && lane < TT) {
      float acc = -FLT_MAX;
#pragma unroll 4
      for (int j = 0; j < TT; ++j) acc = fmaxf(acc, trans[lane * TT + j] - trans[j]);
      rc = acc + 1e-3f;
    }
    const int tkA = tok_ids[b * SS];
    const float* er = emb + (size_t)tkA * EE;
    float x = bias[jj] + start_t[jj];
#pragma unroll
    for (int d = 0; d < EE; ++d) x = fmaf(er[d], W[jj * EE + d], x);
    const float x0 = __shfl(x, 0, 64);
    const bool okl = (lane == 0 || lane >= TT) ? true : (x + rc <= x0);
    if (!__all(okl) && lane == 0) atomicOr(&s_fail, 1);
  }
  if (tid >= 960) {
    // wave 15: final tag = argmax_j( em + b + trans[0][j] + end[j] ), ties->low
    const int tkL = tok_ids[b * SS + SS - 1];
    const float* er = emb + (size_t)tkL * EE;
    float y = bias[jj] + trans[jj] + end_t[jj];
#pragma unroll
    for (int d = 0; d < EE; ++d) y = fmaf(er[d], W[jj * EE + d], y);
    if (lane >= TT) y = -FLT_MAX;
    int idx = lane;
#pragma unroll
    for (int m = 32; m; m >>= 1) {
      const float oy = __shfl_xor(y, m, 64);
      const int oi = __shfl_xor(idx, m, 64);
      if (oy > y || (oy == y && oi < idx)) { y = oy; idx = oi; }
    }
    wtag = idx;
  }
  int4 z = make_int4(0, 0, 0, 0);
  if (tid == 1023) z.w = wtag;
  *(int4*)(out + b * SS + p0) = z;

  __syncthreads();
  if (s_fail == 0) return;

  // ---- exact sequential fallback (reference semantics), wave 0 only ----
  if (tid >= 64) return;   // no further barriers below
  unsigned char* __restrict__ bp = bp_all + (size_t)b * (SS - 1) * TT;
  float w[EE];
#pragma unroll
  for (int d = 0; d < EE; ++d) w[d] = W[jj * EE + d];
  const float bj = bias[jj];
  float sc;
  {
    const int tkq = tok_ids[b * SS];
    const float* er = emb + (size_t)tkq * EE;
    float em = bj;
#pragma unroll
    for (int d = 0; d < EE; ++d) em = fmaf(er[d], w[d], em);
    sc = start_t[jj] + em;
  }
  for (int t = 1; t < SS; ++t) {
    const int tkq = tok_ids[b * SS + t];
    const float* er = emb + (size_t)tkq * EE;
    float em = bj;
#pragma unroll
    for (int d = 0; d < EE; ++d) em = fmaf(er[d], w[d], em);
    float best = -FLT_MAX; int bpi = 0;
#pragma unroll 1
    for (int i = 0; i < TT; ++i) {
      const float v = (__shfl(sc, i, 64) + trans[i * TT + jj]) + em;
      if (v > best) { best = v; bpi = i; }
    }
    if (lane < TT) bp[(size_t)(t - 1) * TT + lane] = (unsigned char)bpi;
    sc = best;
  }
  {
    float y = sc + end_t[jj];
    if (lane >= TT) y = -FLT_MAX;
    int idx = lane;
#pragma unroll
    for (int m = 32; m; m >>= 1) {
      const float oy = __shfl_xor(y, m, 64);
      const int oi = __shfl_xor(idx, m, 64);
      if (oy > y || (oy == y && oi < idx)) { y = oy; idx = oi; }
    }
    if (lane == 0) {
      int curtag = idx;
      out[b * SS + (SS - 1)] = curtag;
      for (int t = SS - 2; t >= 0; --t) {
        curtag = bp[(size_t)t * TT + curtag];
        out[b * SS + t] = curtag;
      }
    }
  }
}

extern "C" void kernel_launch(void* const* d_in, const int* in_sizes, int n_in,
                              void* d_out, int out_size, void* d_ws, size_t ws_size,
                              hipStream_t stream) {
  const int*   tok_ids = (const int*)d_in[0];
  const float* emb     = (const float*)d_in[1];
  const float* W       = (const float*)d_in[2];
  const float* bias    = (const float*)d_in[3];
  const float* start_t = (const float*)d_in[4];
  const float* end_t   = (const float*)d_in[5];
  const float* trans   = (const float*)d_in[6];
  int* out = (int*)d_out;

  const int vocab = in_sizes[1] / EE;
  unsigned char* safe = (unsigned char*)d_ws;
  unsigned char* bp   = (unsigned char*)d_ws + 131072;

  const int tok_per_block = 4 * TPW;  // 16
  k_vocab<<<(vocab + tok_per_block - 1) / tok_per_block, 256, 0, stream>>>(
      emb, W, bias, trans, safe, vocab);
  k_row<<<BB, 1024, 0, stream>>>(tok_ids, emb, W, bias, start_t, end_t, trans,
                                 safe, out, bp);
}

// Round 8
// 21.074 us; speedup vs baseline: 4.4048x; 1.1036x over previous
//
#include <hip/hip_runtime.h>
#include <hip/hip_bf16.h>
#include <float.h>

#define BB 128
#define SS 4096
#define TT 48
#define EE 10

// ---------------------------------------------------------------------------
// ws layout:
//   [0      .. 65536)  unsigned char safe[vocab]
//   [65536  .. +512 )  int flags[128]     (cleared by k_safe block 0)
//   [131072 .. +25MB)  fallback backpointers (touched only on fallback)
//
// rowC[i] = max_j(trans[i][j] - trans[0][j]) + 1e-3 is state-independent: for
// ANY state x, (forall i>=1: x_i + rowC[i] <= x_0) => the Viterbi argmax row
// out of x is all-O (tag 0), margin absorbing f32 rounding. Induction over
// steps: if every step's argmax row is all-O, canonical scores stay
// x_t + const, so the per-token test is an exact validity certificate. A
// spurious failure only triggers the exact fallback, never wrongness.
// ---------------------------------------------------------------------------

// Node 1: one THREAD per token (fast: ~42 cyc/token/wave). W rows + folded
// per-tag thresholds staged in LDS; all lanes read the same LDS address ->
// broadcast, conflict-free. safe[tok]=1 iff canonical state is all-O-dominated.
__global__ __launch_bounds__(256) void k_safe(
    const float* __restrict__ emb, const float* __restrict__ W,
    const float* __restrict__ bias, const float* __restrict__ trans,
    unsigned char* __restrict__ safe, int* __restrict__ flags, int vocab)
{
  // sW[i][0..9] = W row i; sW[i][10] = bias_i + trans[0][i] + rowC_i (i>=1)
  //                        sW[0][10] = bias_0 + trans[0][0]
  __shared__ float sW[TT][12];
  const int tid = threadIdx.x;

  for (int idx = tid; idx < TT * EE; idx += 256) sW[idx / EE][idx % EE] = W[idx];
  if (tid < TT) {
    const float base = bias[tid] + trans[tid];       // bias_i + trans[0][i]
    if (tid == 0) {
      sW[0][10] = base;
    } else {
      float acc = -FLT_MAX;
#pragma unroll 1
      for (int j = 0; j < TT; ++j) acc = fmaxf(acc, trans[tid * TT + j] - trans[j]);
      sW[tid][10] = base + acc + 1e-3f;              // base_i + rowC_i
    }
    sW[tid][11] = 0.0f;
  }
  if (blockIdx.x == 0 && tid < BB) flags[tid] = 0;
  __syncthreads();

  const int tok = blockIdx.x * 256 + tid;
  if (tok >= vocab) return;

  // emb row: 40 B, 8-byte aligned -> five float2 loads (coalesced across lanes)
  const float2* er = (const float2*)(emb + (size_t)tok * EE);
  const float2 e01 = er[0], e23 = er[1], e45 = er[2], e67 = er[3], e89 = er[4];

  float x0;
  {
    const float4* r = (const float4*)sW[0];
    const float4 a = r[0], bq = r[1], c = r[2];
    float x = c.z;
    x = fmaf(e01.x, a.x, x); x = fmaf(e01.y, a.y, x);
    x = fmaf(e23.x, a.z, x); x = fmaf(e23.y, a.w, x);
    x = fmaf(e45.x, bq.x, x); x = fmaf(e45.y, bq.y, x);
    x = fmaf(e67.x, bq.z, x); x = fmaf(e67.y, bq.w, x);
    x = fmaf(e89.x, c.x, x); x = fmaf(e89.y, c.y, x);
    x0 = x;
  }
  int ok = 1;
#pragma unroll 8
  for (int i = 1; i < TT; ++i) {
    const float4* r = (const float4*)sW[i];
    const float4 a = r[0], bq = r[1], c = r[2];
    float x = c.z;                                    // base_i + rowC_i
    x = fmaf(e01.x, a.x, x); x = fmaf(e01.y, a.y, x);
    x = fmaf(e23.x, a.z, x); x = fmaf(e23.y, a.w, x);
    x = fmaf(e45.x, bq.x, x); x = fmaf(e45.y, bq.y, x);
    x = fmaf(e67.x, bq.z, x); x = fmaf(e67.y, bq.w, x);
    x = fmaf(e89.x, c.x, x); x = fmaf(e89.y, c.y, x);
    ok &= (x <= x0);
  }
  safe[tok] = (unsigned char)ok;
}

// Node 2: 4 blocks per row, 1 int4 (4 positions) per thread. Zero-fill +
// safe-gather; chunk-0 wave 0: exact t=0 check (start bias, inline rowC);
// chunk-3 wave 3: final tag fused into thread 255's store. atomicOr only
// executes on failure (never, on this data) -> zero atomic traffic.
__global__ __launch_bounds__(256) void k_body(
    const int* __restrict__ tok_ids, const float* __restrict__ emb,
    const float* __restrict__ W, const float* __restrict__ bias,
    const float* __restrict__ start_t, const float* __restrict__ end_t,
    const float* __restrict__ trans, const unsigned char* __restrict__ safe,
    int* __restrict__ out, int* __restrict__ flags)
{
  const int bid = blockIdx.x;
  const int b = bid >> 2, chunk = bid & 3;
  const int tid = threadIdx.x;
  const int lane = tid & 63;
  const int jj = lane < TT ? lane : TT - 1;
  const int p0 = chunk * 1024 + tid * 4;

  const int4 tk = *(const int4*)(tok_ids + b * SS + p0);
  int fail = 0;
  if (p0 != 0)          fail |= !safe[tk.x];     // t=0 handled exactly below
  fail |= !safe[tk.y];
  fail |= !safe[tk.z];
  if (p0 + 3 != SS - 1) fail |= !safe[tk.w];     // S-1 has no outgoing check
  if (fail) atomicOr(&flags[b], 1);

  int wtag = 0;
  if (chunk == 0 && tid < 64) {
    // exact t=0 check: state uses start bias; per-lane rowC inline (trans L1)
    float rc = 0.0f;
    if (lane >= 1 && lane < TT) {
      float acc = -FLT_MAX;
#pragma unroll 4
      for (int j = 0; j < TT; ++j) acc = fmaxf(acc, trans[lane * TT + j] - trans[j]);
      rc = acc + 1e-3f;
    }
    const int tkA = tok_ids[b * SS];
    const float* er = emb + (size_t)tkA * EE;
    float x = bias[jj] + start_t[jj];
#pragma unroll
    for (int d = 0; d < EE; ++d) x = fmaf(er[d], W[jj * EE + d], x);
    const float x0 = __shfl(x, 0, 64);
    const bool okl = (lane == 0 || lane >= TT) ? true : (x + rc <= x0);
    if (!__all(okl) && lane == 0) atomicOr(&flags[b], 1);
  }
  if (chunk == 3 && tid >= 192) {
    // final tag = argmax_j( em + b + trans[0][j] + end[j] ), ties -> lowest j
    const int tkL = tok_ids[b * SS + SS - 1];
    const float* er = emb + (size_t)tkL * EE;
    float y = bias[jj] + trans[jj] + end_t[jj];
#pragma unroll
    for (int d = 0; d < EE; ++d) y = fmaf(er[d], W[jj * EE + d], y);
    if (lane >= TT) y = -FLT_MAX;
    int idx = lane;
#pragma unroll
    for (int m = 32; m; m >>= 1) {
      const float oy = __shfl_xor(y, m, 64);
      const int oi = __shfl_xor(idx, m, 64);
      if (oy > y || (oy == y && oi < idx)) { y = oy; idx = oi; }
    }
    wtag = idx;
  }
  int4 z = make_int4(0, 0, 0, 0);
  if (chunk == 3 && tid == 255) z.w = wtag;
  *(int4*)(out + b * SS + p0) = z;
}

// Node 3: exact sequential fallback (reference semantics), early-exit.
__global__ __launch_bounds__(64) void k_fallback(
    const int* __restrict__ tok_ids, const float* __restrict__ emb,
    const float* __restrict__ W, const float* __restrict__ bias,
    const float* __restrict__ start_t, const float* __restrict__ end_t,
    const float* __restrict__ trans, int* __restrict__ out,
    const int* __restrict__ flags, unsigned char* __restrict__ bp_all)
{
  const int b = blockIdx.x;
  if (flags[b] == 0) return;

  const int lane = threadIdx.x;
  const int jj = lane < TT ? lane : TT - 1;
  unsigned char* __restrict__ bp = bp_all + (size_t)b * (SS - 1) * TT;
  float w[EE];
#pragma unroll
  for (int d = 0; d < EE; ++d) w[d] = W[jj * EE + d];
  const float bj = bias[jj];

  float sc;
  {
    const int tk = tok_ids[b * SS];
    const float* er = emb + (size_t)tk * EE;
    float em = bj;
#pragma unroll
    for (int d = 0; d < EE; ++d) em = fmaf(er[d], w[d], em);
    sc = start_t[jj] + em;
  }
  for (int t = 1; t < SS; ++t) {
    const int tk = tok_ids[b * SS + t];
    const float* er = emb + (size_t)tk * EE;
    float em = bj;
#pragma unroll
    for (int d = 0; d < EE; ++d) em = fmaf(er[d], w[d], em);
    float best = -FLT_MAX; int bpi = 0;
#pragma unroll 1
    for (int i = 0; i < TT; ++i) {
      const float v = (__shfl(sc, i, 64) + trans[i * TT + jj]) + em;
      if (v > best) { best = v; bpi = i; }
    }
    if (lane < TT) bp[(size_t)(t - 1) * TT + lane] = (unsigned char)bpi;
    sc = best;
  }
  {
    float y = sc + end_t[jj];
    if (lane >= TT) y = -FLT_MAX;
    int idx = lane;
#pragma unroll
    for (int m = 32; m; m >>= 1) {
      const float oy = __shfl_xor(y, m, 64);
      const int oi = __shfl_xor(idx, m, 64);
      if (oy > y || (oy == y && oi < idx)) { y = oy; idx = oi; }
    }
    if (lane == 0) {
      int curtag = idx;
      out[b * SS + (SS - 1)] = curtag;
      for (int t = SS - 2; t >= 0; --t) {
        curtag = bp[(size_t)t * TT + curtag];
        out[b * SS + t] = curtag;
      }
    }
  }
}

extern "C" void kernel_launch(void* const* d_in, const int* in_sizes, int n_in,
                              void* d_out, int out_size, void* d_ws, size_t ws_size,
                              hipStream_t stream) {
  const int*   tok_ids = (const int*)d_in[0];
  const float* emb     = (const float*)d_in[1];
  const float* W       = (const float*)d_in[2];
  const float* bias    = (const float*)d_in[3];
  const float* start_t = (const float*)d_in[4];
  const float* end_t   = (const float*)d_in[5];
  const float* trans   = (const float*)d_in[6];
  int* out = (int*)d_out;

  const int vocab = in_sizes[1] / EE;
  unsigned char* safe  = (unsigned char*)d_ws;
  int*           flags = (int*)((char*)d_ws + 65536);
  unsigned char* bp    = (unsigned char*)d_ws + 131072;

  k_safe<<<(vocab + 255) / 256, 256, 0, stream>>>(emb, W, bias, trans, safe,
                                                  flags, vocab);
  k_body<<<BB * 4, 256, 0, stream>>>(tok_ids, emb, W, bias, start_t, end_t,
                                     trans, safe, out, flags);
  k_fallback<<<BB, 64, 0, stream>>>(tok_ids, emb, W, bias, start_t, end_t,
                                    trans, out, flags, bp);
}

// Round 9
// 18.102 us; speedup vs baseline: 5.1278x; 1.1641x over previous
//
#include <hip/hip_runtime.h>
#include <hip/hip_bf16.h>
#include <float.h>

#define BB 128
#define SS 4096
#define TT 48
#define EE 10

// ---------------------------------------------------------------------------
// ws layout:
//   [0      .. 65536)  unsigned char safe[vocab]
//   [65536  .. +512 )  int flags[128]   (written by k_safe special block: 0/1)
//   [66560  .. +512 )  int ftag[128]    (final tag per row, k_safe special blk)
//   [131072 .. +25MB)  fallback backpointers (touched only on fallback)
//
// rowC[i] = max_j(trans[i][j] - trans[0][j]) + 1e-3 is state-independent: for
// ANY score vector x, (forall i>=1: x_i + rowC[i] <= x_0) => the Viterbi
// argmax row out of x is all-O (tag 0), margin absorbing f32 rounding.
// Induction over steps: if the t=0 state (start bias) and every interior
// token pass, scores stay canonical (x_t + const), so the per-token test is
// an exact validity certificate. Spurious failure only triggers the exact
// sequential fallback, never wrongness.
// ---------------------------------------------------------------------------

__device__ __forceinline__ float dot10(const float* __restrict__ r,
                                       float2 e01, float2 e23, float2 e45,
                                       float2 e67, float2 e89) {
  float x = 0.0f;
  x = fmaf(e01.x, r[0], x); x = fmaf(e01.y, r[1], x);
  x = fmaf(e23.x, r[2], x); x = fmaf(e23.y, r[3], x);
  x = fmaf(e45.x, r[4], x); x = fmaf(e45.y, r[5], x);
  x = fmaf(e67.x, r[6], x); x = fmaf(e67.y, r[7], x);
  x = fmaf(e89.x, r[8], x); x = fmaf(e89.y, r[9], x);
  return x;
}

// Node 1: blocks 0..nb-1: one THREAD per token, W + folded thresholds in LDS
// (uniform-address broadcast reads). Last block (special): 128 threads do the
// exact t=0 start-checks -> flags[b], 128 threads do final tags -> ftag[b].
__global__ __launch_bounds__(256) void k_safe(
    const float* __restrict__ emb, const float* __restrict__ W,
    const float* __restrict__ bias, const float* __restrict__ start_t,
    const float* __restrict__ end_t, const float* __restrict__ trans,
    const int* __restrict__ tok_ids, unsigned char* __restrict__ safe,
    int* __restrict__ flags, int* __restrict__ ftag, int vocab)
{
  // sW[i][0..9] = W row i; sW[i][10] = bias_i + trans[0][i] (+ rowC_i, i>=1)
  __shared__ float sW[TT][12];
  __shared__ float sStart[TT];   // bias_i + start_i (+ rowC_i, i>=1)
  __shared__ float sFin[TT];     // bias_j + trans[0][j] + end_j
  const int tid = threadIdx.x;
  const bool special = (blockIdx.x == gridDim.x - 1);

  for (int idx = tid; idx < TT * EE; idx += 256) sW[idx / EE][idx % EE] = W[idx];

  if (!special) {
    if (tid < TT) {
      const float base = bias[tid] + trans[tid];       // bias_i + trans[0][i]
      if (tid == 0) {
        sW[0][10] = base;
      } else {
        float acc = -FLT_MAX;
#pragma unroll 1
        for (int j = 0; j < TT; ++j) acc = fmaxf(acc, trans[tid * TT + j] - trans[j]);
        sW[tid][10] = base + acc + 1e-3f;              // base_i + rowC_i
      }
      sW[tid][11] = 0.0f;
    }
    __syncthreads();

    const int tok = blockIdx.x * 256 + tid;
    if (tok >= vocab) return;

    const float2* er = (const float2*)(emb + (size_t)tok * EE);
    const float2 e01 = er[0], e23 = er[1], e45 = er[2], e67 = er[3], e89 = er[4];

    float x0;
    {
      const float4* r = (const float4*)sW[0];
      const float4 a = r[0], bq = r[1], c = r[2];
      float x = c.z;
      x = fmaf(e01.x, a.x, x); x = fmaf(e01.y, a.y, x);
      x = fmaf(e23.x, a.z, x); x = fmaf(e23.y, a.w, x);
      x = fmaf(e45.x, bq.x, x); x = fmaf(e45.y, bq.y, x);
      x = fmaf(e67.x, bq.z, x); x = fmaf(e67.y, bq.w, x);
      x = fmaf(e89.x, c.x, x); x = fmaf(e89.y, c.y, x);
      x0 = x;
    }
    int ok = 1;
#pragma unroll 8
    for (int i = 1; i < TT; ++i) {
      const float4* r = (const float4*)sW[i];
      const float4 a = r[0], bq = r[1], c = r[2];
      float x = c.z;                                    // base_i + rowC_i
      x = fmaf(e01.x, a.x, x); x = fmaf(e01.y, a.y, x);
      x = fmaf(e23.x, a.z, x); x = fmaf(e23.y, a.w, x);
      x = fmaf(e45.x, bq.x, x); x = fmaf(e45.y, bq.y, x);
      x = fmaf(e67.x, bq.z, x); x = fmaf(e67.y, bq.w, x);
      x = fmaf(e89.x, c.x, x); x = fmaf(e89.y, c.y, x);
      ok &= (x <= x0);
    }
    safe[tok] = (unsigned char)ok;
    return;
  }

  // ---- special block: per-row t=0 verdicts + final tags ----
  if (tid < TT) {
    float rc = 0.0f;
    if (tid >= 1) {
      float acc = -FLT_MAX;
#pragma unroll 1
      for (int j = 0; j < TT; ++j) acc = fmaxf(acc, trans[tid * TT + j] - trans[j]);
      rc = acc + 1e-3f;
    }
    sStart[tid] = bias[tid] + start_t[tid] + rc;
    sFin[tid]   = bias[tid] + trans[tid] + end_t[tid];
  }
  __syncthreads();

  if (tid < BB) {
    // exact t=0 check for row b: state x = bias + start + em(tok0)·W
    const int b = tid;
    const int tk = tok_ids[(size_t)b * SS];
    const float2* er = (const float2*)(emb + (size_t)tk * EE);
    const float2 e01 = er[0], e23 = er[1], e45 = er[2], e67 = er[3], e89 = er[4];
    const float x0 = dot10(sW[0], e01, e23, e45, e67, e89) + sStart[0];
    int ok = 1;
#pragma unroll 4
    for (int i = 1; i < TT; ++i)
      ok &= (dot10(sW[i], e01, e23, e45, e67, e89) + sStart[i] <= x0);
    flags[b] = ok ? 0 : 1;
  } else {
    // final tag for row b: argmax_j( em(tokL)·W_j + bias_j+trans[0][j]+end_j )
    const int b = tid - BB;
    const int tk = tok_ids[(size_t)b * SS + SS - 1];
    const float2* er = (const float2*)(emb + (size_t)tk * EE);
    const float2 e01 = er[0], e23 = er[1], e45 = er[2], e67 = er[3], e89 = er[4];
    float best = dot10(sW[0], e01, e23, e45, e67, e89) + sFin[0];
    int bi = 0;
#pragma unroll 4
    for (int j = 1; j < TT; ++j) {
      const float y = dot10(sW[j], e01, e23, e45, e67, e89) + sFin[j];
      if (y > best) { best = y; bi = j; }   // strict > keeps lowest j on ties
    }
    ftag[b] = bi;
  }
}

// Node 2: one block per row, 256 threads, 4 int4 each. Pure streaming:
// verdict = flags[b] | gather-fails (LDS OR, no fences). Clean: zero-stores
// with ftag fused into the last int4. Flagged (never on this data): wave 0
// runs the exact sequential reference Viterbi; no other thread stores.
__global__ __launch_bounds__(256) void k_row(
    const int* __restrict__ tok_ids, const float* __restrict__ emb,
    const float* __restrict__ W, const float* __restrict__ bias,
    const float* __restrict__ start_t, const float* __restrict__ end_t,
    const float* __restrict__ trans, const unsigned char* __restrict__ safe,
    const int* __restrict__ flags, const int* __restrict__ ftag,
    int* __restrict__ out, unsigned char* __restrict__ bp_all)
{
  __shared__ int s_fail;
  const int b = blockIdx.x;
  const int tid = threadIdx.x;
  const int ft = (tid == 255) ? ftag[b] : 0;   // prefetch before barrier
  if (tid == 0) s_fail = flags[b];
  __syncthreads();

  const int4* trow = (const int4*)(tok_ids + (size_t)b * SS);
  int4 tk[4];
#pragma unroll
  for (int q = 0; q < 4; ++q) tk[q] = trow[tid * 4 + q];
  int fail = 0;
#pragma unroll
  for (int q = 0; q < 4; ++q) {
    const int p = tid * 16 + q * 4;
    if (p != 0)          fail |= !safe[tk[q].x];   // t=0 covered by flags[b]
    fail |= !safe[tk[q].y];
    fail |= !safe[tk[q].z];
    if (p + 3 != SS - 1) fail |= !safe[tk[q].w];   // S-1: no outgoing check
  }
  if (fail) atomicOr(&s_fail, 1);                  // LDS atomic
  __syncthreads();

  if (s_fail == 0) {
    int4* orow = (int4*)(out + (size_t)b * SS);
    const int4 z = make_int4(0, 0, 0, 0);
#pragma unroll
    for (int q = 0; q < 3; ++q) orow[tid * 4 + q] = z;
    int4 zl = z;
    if (tid == 255) zl.w = ft;
    orow[tid * 4 + 3] = zl;
    return;
  }

  // ---- exact sequential fallback (reference semantics), wave 0 only ----
  if (tid >= 64) return;                           // no barriers below
  const int lane = tid;
  const int jj = lane < TT ? lane : TT - 1;
  unsigned char* __restrict__ bp = bp_all + (size_t)b * (SS - 1) * TT;
  float w[EE];
#pragma unroll
  for (int d = 0; d < EE; ++d) w[d] = W[jj * EE + d];
  const float bj = bias[jj];

  float sc;
  {
    const int tkq = tok_ids[(size_t)b * SS];
    const float* er = emb + (size_t)tkq * EE;
    float em = bj;
#pragma unroll
    for (int d = 0; d < EE; ++d) em = fmaf(er[d], w[d], em);
    sc = start_t[jj] + em;
  }
  for (int t = 1; t < SS; ++t) {
    const int tkq = tok_ids[(size_t)b * SS + t];
    const float* er = emb + (size_t)tkq * EE;
    float em = bj;
#pragma unroll
    for (int d = 0; d < EE; ++d) em = fmaf(er[d], w[d], em);
    float best = -FLT_MAX; int bpi = 0;
#pragma unroll 1
    for (int i = 0; i < TT; ++i) {
      const float v = (__shfl(sc, i, 64) + trans[i * TT + jj]) + em;
      if (v > best) { best = v; bpi = i; }
    }
    if (lane < TT) bp[(size_t)(t - 1) * TT + lane] = (unsigned char)bpi;
    sc = best;
  }
  {
    float y = sc + end_t[jj];
    if (lane >= TT) y = -FLT_MAX;
    int idx = lane;
#pragma unroll
    for (int m = 32; m; m >>= 1) {
      const float oy = __shfl_xor(y, m, 64);
      const int oi = __shfl_xor(idx, m, 64);
      if (oy > y || (oy == y && oi < idx)) { y = oy; idx = oi; }
    }
    if (lane == 0) {
      int curtag = idx;
      out[(size_t)b * SS + (SS - 1)] = curtag;
      for (int t = SS - 2; t >= 0; --t) {
        curtag = bp[(size_t)t * TT + curtag];
        out[(size_t)b * SS + t] = curtag;
      }
    }
  }
}

extern "C" void kernel_launch(void* const* d_in, const int* in_sizes, int n_in,
                              void* d_out, int out_size, void* d_ws, size_t ws_size,
                              hipStream_t stream) {
  const int*   tok_ids = (const int*)d_in[0];
  const float* emb     = (const float*)d_in[1];
  const float* W       = (const float*)d_in[2];
  const float* bias    = (const float*)d_in[3];
  const float* start_t = (const float*)d_in[4];
  const float* end_t   = (const float*)d_in[5];
  const float* trans   = (const float*)d_in[6];
  int* out = (int*)d_out;

  const int vocab = in_sizes[1] / EE;
  unsigned char* safe  = (unsigned char*)d_ws;
  int*           flags = (int*)((char*)d_ws + 65536);
  int*           ftag  = (int*)((char*)d_ws + 66560);
  unsigned char* bp    = (unsigned char*)d_ws + 131072;

  const int nb = (vocab + 255) / 256;   // token blocks; +1 special block
  k_safe<<<nb + 1, 256, 0, stream>>>(emb, W, bias, start_t, end_t, trans,
                                     tok_ids, safe, flags, ftag, vocab);
  k_row<<<BB, 256, 0, stream>>>(tok_ids, emb, W, bias, start_t, end_t, trans,
                                safe, flags, ftag, out, bp);
}

// Round 10
// 16.984 us; speedup vs baseline: 5.4653x; 1.0658x over previous
//
#include <hip/hip_runtime.h>
#include <hip/hip_bf16.h>
#include <float.h>

#define BB 128
#define SS 4096
#define TT 48
#define EE 10

// ---------------------------------------------------------------------------
// ws layout:
//   [0      .. 8192 )  unsigned long long safe_bits[vocab/64]  (bit per token)
//   [65536  .. +512 )  int flags[128]   (k_safe special block: 0/1 per row)
//   [66560  .. +512 )  int ftag[128]    (final tag per row)
//   [131072 .. +25MB)  fallback backpointers (touched only on fallback)
//
// rowC[i] = max_j(trans[i][j] - trans[0][j]) + 1e-3 is state-independent: for
// ANY score vector x, (forall i>=1: x_i + rowC[i] <= x_0) => the Viterbi
// argmax row out of x is all-O (tag 0), margin absorbing f32 rounding.
// Induction: if the t=0 state (start bias) and every interior token pass,
// scores stay canonical (x_t + const), so the per-token test is an exact
// validity certificate. Spurious failure only triggers the exact sequential
// fallback, never wrongness.
// ---------------------------------------------------------------------------

__device__ __forceinline__ float dot10(const float* __restrict__ r,
                                       float2 e01, float2 e23, float2 e45,
                                       float2 e67, float2 e89) {
  float x = 0.0f;
  x = fmaf(e01.x, r[0], x); x = fmaf(e01.y, r[1], x);
  x = fmaf(e23.x, r[2], x); x = fmaf(e23.y, r[3], x);
  x = fmaf(e45.x, r[4], x); x = fmaf(e45.y, r[5], x);
  x = fmaf(e67.x, r[6], x); x = fmaf(e67.y, r[7], x);
  x = fmaf(e89.x, r[8], x); x = fmaf(e89.y, r[9], x);
  return x;
}

// Node 1: blocks 0..nb-1: one THREAD per token; verdicts bit-packed via
// __ballot -> 6.3KB table (L1-resident for node 2). Last block: 128 threads
// do exact t=0 start-checks -> flags[b], 128 threads do final tags -> ftag[b].
__global__ __launch_bounds__(256) void k_safe(
    const float* __restrict__ emb, const float* __restrict__ W,
    const float* __restrict__ bias, const float* __restrict__ start_t,
    const float* __restrict__ end_t, const float* __restrict__ trans,
    const int* __restrict__ tok_ids, unsigned long long* __restrict__ safe_bits,
    int* __restrict__ flags, int* __restrict__ ftag, int vocab)
{
  // sW[i][0..9] = W row i; sW[i][10] = bias_i + trans[0][i] (+ rowC_i, i>=1)
  __shared__ float sW[TT][12];
  __shared__ float sStart[TT];   // bias_i + start_i (+ rowC_i, i>=1)
  __shared__ float sFin[TT];     // bias_j + trans[0][j] + end_j
  const int tid = threadIdx.x;
  const bool special = (blockIdx.x == gridDim.x - 1);

  for (int idx = tid; idx < TT * EE; idx += 256) sW[idx / EE][idx % EE] = W[idx];

  if (!special) {
    if (tid < TT) {
      const float base = bias[tid] + trans[tid];       // bias_i + trans[0][i]
      if (tid == 0) {
        sW[0][10] = base;
      } else {
        float acc = -FLT_MAX;
#pragma unroll 1
        for (int j = 0; j < TT; ++j) acc = fmaxf(acc, trans[tid * TT + j] - trans[j]);
        sW[tid][10] = base + acc + 1e-3f;              // base_i + rowC_i
      }
      sW[tid][11] = 0.0f;
    }
    __syncthreads();

    const int tok = blockIdx.x * 256 + tid;
    const bool live = tok < vocab;
    // OOB lanes read token 0 (harmless) and force ok=1 (padding bits safe).
    const int tok_ld = live ? tok : 0;
    const float2* er = (const float2*)(emb + (size_t)tok_ld * EE);
    const float2 e01 = er[0], e23 = er[1], e45 = er[2], e67 = er[3], e89 = er[4];

    float x0;
    {
      const float4* r = (const float4*)sW[0];
      const float4 a = r[0], bq = r[1], c = r[2];
      float x = c.z;
      x = fmaf(e01.x, a.x, x); x = fmaf(e01.y, a.y, x);
      x = fmaf(e23.x, a.z, x); x = fmaf(e23.y, a.w, x);
      x = fmaf(e45.x, bq.x, x); x = fmaf(e45.y, bq.y, x);
      x = fmaf(e67.x, bq.z, x); x = fmaf(e67.y, bq.w, x);
      x = fmaf(e89.x, c.x, x); x = fmaf(e89.y, c.y, x);
      x0 = x;
    }
    int ok = 1;
#pragma unroll 8
    for (int i = 1; i < TT; ++i) {
      const float4* r = (const float4*)sW[i];
      const float4 a = r[0], bq = r[1], c = r[2];
      float x = c.z;                                    // base_i + rowC_i
      x = fmaf(e01.x, a.x, x); x = fmaf(e01.y, a.y, x);
      x = fmaf(e23.x, a.z, x); x = fmaf(e23.y, a.w, x);
      x = fmaf(e45.x, bq.x, x); x = fmaf(e45.y, bq.y, x);
      x = fmaf(e67.x, bq.z, x); x = fmaf(e67.y, bq.w, x);
      x = fmaf(e89.x, c.x, x); x = fmaf(e89.y, c.y, x);
      ok &= (x <= x0);
    }
    ok |= !live;                                        // pad bits = safe
    const unsigned long long bits = __ballot(ok);       // 64 verdicts/wave
    if ((tid & 63) == 0)
      safe_bits[(blockIdx.x * 256 + tid) >> 6] = bits;
    return;
  }

  // ---- special block: per-row t=0 verdicts + final tags ----
  if (tid < TT) {
    float rc = 0.0f;
    if (tid >= 1) {
      float acc = -FLT_MAX;
#pragma unroll 1
      for (int j = 0; j < TT; ++j) acc = fmaxf(acc, trans[tid * TT + j] - trans[j]);
      rc = acc + 1e-3f;
    }
    sStart[tid] = bias[tid] + start_t[tid] + rc;
    sFin[tid]   = bias[tid] + trans[tid] + end_t[tid];
  }
  __syncthreads();

  if (tid < BB) {
    // exact t=0 check for row b: state x = bias + start + em(tok0)·W
    const int b = tid;
    const int tk = tok_ids[(size_t)b * SS];
    const float2* er = (const float2*)(emb + (size_t)tk * EE);
    const float2 e01 = er[0], e23 = er[1], e45 = er[2], e67 = er[3], e89 = er[4];
    const float x0 = dot10(sW[0], e01, e23, e45, e67, e89) + sStart[0];
    int ok = 1;
#pragma unroll 4
    for (int i = 1; i < TT; ++i)
      ok &= (dot10(sW[i], e01, e23, e45, e67, e89) + sStart[i] <= x0);
    flags[b] = ok ? 0 : 1;
  } else {
    // final tag for row b: argmax_j( em(tokL)·W_j + bias_j+trans[0][j]+end_j )
    const int b = tid - BB;
    const int tk = tok_ids[(size_t)b * SS + SS - 1];
    const float2* er = (const float2*)(emb + (size_t)tk * EE);
    const float2 e01 = er[0], e23 = er[1], e45 = er[2], e67 = er[3], e89 = er[4];
    float best = dot10(sW[0], e01, e23, e45, e67, e89) + sFin[0];
    int bi = 0;
#pragma unroll 4
    for (int j = 1; j < TT; ++j) {
      const float y = dot10(sW[j], e01, e23, e45, e67, e89) + sFin[j];
      if (y > best) { best = y; bi = j; }   // strict > keeps lowest j on ties
    }
    ftag[b] = bi;
  }
}

// Node 2: one block per row, 1024 threads (16 waves), one int4 each.
// Gathers hit the 6.3KB L1-resident bit-table. Verdict in LDS (no fences).
// Clean: zero-stores with ftag fused into thread 1023's int4. Flagged (never
// on this data): wave 0 runs the exact sequential reference Viterbi.
__global__ __launch_bounds__(1024) void k_row(
    const int* __restrict__ tok_ids, const float* __restrict__ emb,
    const float* __restrict__ W, const float* __restrict__ bias,
    const float* __restrict__ start_t, const float* __restrict__ end_t,
    const float* __restrict__ trans,
    const unsigned char* __restrict__ safe_bytes,   // = (u8*)safe_bits
    const int* __restrict__ flags, const int* __restrict__ ftag,
    int* __restrict__ out, unsigned char* __restrict__ bp_all)
{
  __shared__ int s_fail;
  const int b = blockIdx.x;
  const int tid = threadIdx.x;
  const int ft = (tid == 1023) ? ftag[b] : 0;      // prefetch before barrier
  if (tid == 0) s_fail = flags[b];
  __syncthreads();

  const int p0 = tid * 4;
  const int4 tk = *(const int4*)(tok_ids + (size_t)b * SS + p0);
  int fail = 0;
  if (p0 != 0)
    fail |= !((safe_bytes[tk.x >> 3] >> (tk.x & 7)) & 1);  // t=0 via flags[b]
  fail |= !((safe_bytes[tk.y >> 3] >> (tk.y & 7)) & 1);
  fail |= !((safe_bytes[tk.z >> 3] >> (tk.z & 7)) & 1);
  if (p0 + 3 != SS - 1)
    fail |= !((safe_bytes[tk.w >> 3] >> (tk.w & 7)) & 1);  // S-1: no check
  if (fail) atomicOr(&s_fail, 1);                  // LDS atomic
  __syncthreads();

  if (s_fail == 0) {
    int4 z = make_int4(0, 0, 0, 0);
    if (tid == 1023) z.w = ft;
    *(int4*)(out + (size_t)b * SS + p0) = z;
    return;
  }

  // ---- exact sequential fallback (reference semantics), wave 0 only ----
  if (tid >= 64) return;                           // no barriers below
  const int lane = tid;
  const int jj = lane < TT ? lane : TT - 1;
  unsigned char* __restrict__ bp = bp_all + (size_t)b * (SS - 1) * TT;
  float w[EE];
#pragma unroll
  for (int d = 0; d < EE; ++d) w[d] = W[jj * EE + d];
  const float bj = bias[jj];

  float sc;
  {
    const int tkq = tok_ids[(size_t)b * SS];
    const float* er = emb + (size_t)tkq * EE;
    float em = bj;
#pragma unroll
    for (int d = 0; d < EE; ++d) em = fmaf(er[d], w[d], em);
    sc = start_t[jj] + em;
  }
  for (int t = 1; t < SS; ++t) {
    const int tkq = tok_ids[(size_t)b * SS + t];
    const float* er = emb + (size_t)tkq * EE;
    float em = bj;
#pragma unroll
    for (int d = 0; d < EE; ++d) em = fmaf(er[d], w[d], em);
    float best = -FLT_MAX; int bpi = 0;
#pragma unroll 1
    for (int i = 0; i < TT; ++i) {
      const float v = (__shfl(sc, i, 64) + trans[i * TT + jj]) + em;
      if (v > best) { best = v; bpi = i; }
    }
    if (lane < TT) bp[(size_t)(t - 1) * TT + lane] = (unsigned char)bpi;
    sc = best;
  }
  {
    float y = sc + end_t[jj];
    if (lane >= TT) y = -FLT_MAX;
    int idx = lane;
#pragma unroll
    for (int m = 32; m; m >>= 1) {
      const float oy = __shfl_xor(y, m, 64);
      const int oi = __shfl_xor(idx, m, 64);
      if (oy > y || (oy == y && oi < idx)) { y = oy; idx = oi; }
    }
    if (lane == 0) {
      int curtag = idx;
      out[(size_t)b * SS + (SS - 1)] = curtag;
      for (int t = SS - 2; t >= 0; --t) {
        curtag = bp[(size_t)t * TT + curtag];
        out[(size_t)b * SS + t] = curtag;
      }
    }
  }
}

extern "C" void kernel_launch(void* const* d_in, const int* in_sizes, int n_in,
                              void* d_out, int out_size, void* d_ws, size_t ws_size,
                              hipStream_t stream) {
  const int*   tok_ids = (const int*)d_in[0];
  const float* emb     = (const float*)d_in[1];
  const float* W       = (const float*)d_in[2];
  const float* bias    = (const float*)d_in[3];
  const float* start_t = (const float*)d_in[4];
  const float* end_t   = (const float*)d_in[5];
  const float* trans   = (const float*)d_in[6];
  int* out = (int*)d_out;

  const int vocab = in_sizes[1] / EE;
  unsigned long long* safe_bits = (unsigned long long*)d_ws;
  int*           flags = (int*)((char*)d_ws + 65536);
  int*           ftag  = (int*)((char*)d_ws + 66560);
  unsigned char* bp    = (unsigned char*)d_ws + 131072;

  const int nb = (vocab + 255) / 256;   // token blocks; +1 special block
  k_safe<<<nb + 1, 256, 0, stream>>>(emb, W, bias, start_t, end_t, trans,
                                     tok_ids, safe_bits, flags, ftag, vocab);
  k_row<<<BB, 1024, 0, stream>>>(tok_ids, emb, W, bias, start_t, end_t, trans,
                                 (const unsigned char*)safe_bits, flags, ftag,
                                 out, bp);
}

// Round 11
// 12.321 us; speedup vs baseline: 7.5336x; 1.3784x over previous
//
#include <hip/hip_runtime.h>
#include <hip/hip_bf16.h>
#include <float.h>

#define BB 128
#define SS 4096
#define TT 48
#define EE 10

// ---------------------------------------------------------------------------
// Single-node design. Per row (block): certify every interior position's
// Viterbi argmax row is all-O via a per-token norm test, then write zeros +
// final tag. Certificates (state-independent, induction over steps):
//   rowC_i = max_j(trans[i][j]-trans[0][j]) + 1e-3
//   exact : em·W_i + A_i <= em·W_0 + A_0  for all i>=1,
//           A_i = bias_i + trans[0][i] + rowC_i   (start_t version for t=0)
//   cheap : ||em||^2 <= R^2 = min_i (A_0-A_i)^2/||W_i-W_0||^2  (Cauchy-Schwarz
//           => exact holds). Margin 1e-2 absorbs f32 rounding; b[O]=50 makes
//           R ~ 35 vs ||em|| ~ 3.2, so the cheap test essentially never
//           fails. Failure path: inline exact check -> LDS flag -> exact
//           sequential reference Viterbi (never taken on this data).
// ws: [0 .. 25MB) fallback backpointers only.
// ---------------------------------------------------------------------------

__global__ __launch_bounds__(1024) void k_one(
    const int* __restrict__ tok_ids, const float* __restrict__ emb,
    const float* __restrict__ W, const float* __restrict__ bias,
    const float* __restrict__ start_t, const float* __restrict__ end_t,
    const float* __restrict__ trans, int* __restrict__ out,
    unsigned char* __restrict__ bp_all)
{
  __shared__ float sW[TT][12];   // W rows (10 used)
  __shared__ float sA[TT];       // A_i (mix bias)
  __shared__ float sAs[TT];      // A_i (start bias, t=0)
  __shared__ float sFin[TT];     // bias_j + trans[0][j] + end_j
  __shared__ float sR2, sR2s;
  __shared__ int s_fail, s_ftag;

  const int b = blockIdx.x;
  const int tid = threadIdx.x;
  if (tid == 0) s_fail = 0;

  // ---- setup: wave 0 computes thresholds ----
  if (tid < 64) {
    const int lane = tid;
    const int i = lane < TT ? lane : TT - 1;
    float w[EE];
#pragma unroll
    for (int d = 0; d < EE; ++d) w[d] = W[i * EE + d];
    if (lane < TT) {
#pragma unroll
      for (int d = 0; d < EE; ++d) sW[i][d] = w[d];
      sW[i][10] = 0.0f; sW[i][11] = 0.0f;
    }
    const float bi = bias[i], t0i = trans[i], sti = start_t[i];
    float rc = 0.0f;
    if (lane >= 1 && lane < TT) {
      float a0 = -FLT_MAX, a1 = -FLT_MAX, a2 = -FLT_MAX, a3 = -FLT_MAX;
#pragma unroll
      for (int j = 0; j < TT; j += 4) {
        a0 = fmaxf(a0, trans[i * TT + j + 0] - trans[j + 0]);
        a1 = fmaxf(a1, trans[i * TT + j + 1] - trans[j + 1]);
        a2 = fmaxf(a2, trans[i * TT + j + 2] - trans[j + 2]);
        a3 = fmaxf(a3, trans[i * TT + j + 3] - trans[j + 3]);
      }
      rc = fmaxf(fmaxf(a0, a1), fmaxf(a2, a3)) + 1e-3f;
    }
    const float A  = bi + t0i + rc;       // lane 0: rc=0 -> A_0
    const float As = bi + sti + rc;
    if (lane < TT) { sA[i] = A; sAs[i] = As; sFin[i] = bi + t0i + end_t[i]; }
    const float A0  = __shfl(A, 0, 64);
    const float As0 = __shfl(As, 0, 64);
    float dd = 0.0f;
#pragma unroll
    for (int d = 0; d < EE; ++d) {
      const float w0d = __shfl(w[d], 0, 64);
      const float dv = w[d] - w0d;
      dd = fmaf(dv, dv, dd);
    }
    float ratio, ratioS;
    if (lane >= 1 && lane < TT) {
      const float c  = A - A0;            // want <= -margin
      const float cs = As - As0;
      const float ddc = fmaxf(dd, 1e-30f);
      ratio  = (c  < -1e-2f) ? (c * c)   / ddc : -1.0f;
      ratioS = (cs < -1e-2f) ? (cs * cs) / ddc : -1.0f;
    } else { ratio = FLT_MAX; ratioS = FLT_MAX; }
#pragma unroll
    for (int m = 32; m; m >>= 1) {
      ratio  = fminf(ratio,  __shfl_xor(ratio,  m, 64));
      ratioS = fminf(ratioS, __shfl_xor(ratioS, m, 64));
    }
    if (lane == 0) { sR2 = ratio; sR2s = ratioS; }
  }
  __syncthreads();

  // ---- main: 4 positions per thread, norm test per token ----
  const float R2 = sR2, R2s = sR2s;
  const int4 tk = *(const int4*)(tok_ids + (size_t)b * SS + tid * 4);
  int fail = 0;
#pragma unroll
  for (int q = 0; q < 4; ++q) {
    const int tok = (q == 0) ? tk.x : (q == 1) ? tk.y : (q == 2) ? tk.z : tk.w;
    const int p = tid * 4 + q;
    if (p == SS - 1) continue;            // last position: no outgoing check
    const float2* er = (const float2*)(emb + (size_t)tok * EE);
    const float2 e01 = er[0], e23 = er[1], e45 = er[2], e67 = er[3], e89 = er[4];
    float nn = 0.0f;
    nn = fmaf(e01.x, e01.x, nn); nn = fmaf(e01.y, e01.y, nn);
    nn = fmaf(e23.x, e23.x, nn); nn = fmaf(e23.y, e23.y, nn);
    nn = fmaf(e45.x, e45.x, nn); nn = fmaf(e45.y, e45.y, nn);
    nn = fmaf(e67.x, e67.x, nn); nn = fmaf(e67.y, e67.y, nn);
    nn = fmaf(e89.x, e89.x, nn); nn = fmaf(e89.y, e89.y, nn);
    const bool first = (p == 0);
    if (nn > (first ? R2s : R2)) {
      // exact rowC check (cold path)
      const float* __restrict__ A = first ? sAs : sA;
      float x0 = A[0];
#pragma unroll
      for (int d = 0; d < EE; ++d)
        x0 = fmaf(((const float*)er)[d], sW[0][d], x0);
      int ok = 1;
#pragma unroll 4
      for (int i = 1; i < TT; ++i) {
        float x = A[i];
#pragma unroll
        for (int d = 0; d < EE; ++d)
          x = fmaf(((const float*)er)[d], sW[i][d], x);
        ok &= (x <= x0);
      }
      if (!ok) fail = 1;
    }
  }
  if (fail) atomicOr(&s_fail, 1);         // LDS atomic, never on this data

  // ---- wave 15: final tag = argmax_j( em_last·W_j + sFin[j] ), ties->low ----
  if ((tid >> 6) == 15) {
    const int lane = tid & 63;
    const int tkL = __shfl(tk.w, 63, 64); // thread 1023 owns position S-1
    const float* __restrict__ er = emb + (size_t)tkL * EE;  // uniform -> scalar
    const int j = lane < TT ? lane : TT - 1;
    float y = sFin[j];
#pragma unroll
    for (int d = 0; d < EE; ++d) y = fmaf(er[d], sW[j][d], y);
    if (lane >= TT) y = -FLT_MAX;
    int idx = lane;
#pragma unroll
    for (int m = 32; m; m >>= 1) {
      const float oy = __shfl_xor(y, m, 64);
      const int oi = __shfl_xor(idx, m, 64);
      if (oy > y || (oy == y && oi < idx)) { y = oy; idx = oi; }
    }
    if (lane == 0) s_ftag = idx;
  }
  __syncthreads();

  if (s_fail == 0) {
    int4 z = make_int4(0, 0, 0, 0);
    if (tid == 1023) z.w = s_ftag;
    *(int4*)(out + (size_t)b * SS + tid * 4) = z;
    return;
  }

  // ---- exact sequential fallback (reference semantics), wave 0 only ----
  if (tid >= 64) return;                  // no barriers below
  const int lane = tid;
  const int jj = lane < TT ? lane : TT - 1;
  unsigned char* __restrict__ bp = bp_all + (size_t)b * (SS - 1) * TT;
  float w[EE];
#pragma unroll
  for (int d = 0; d < EE; ++d) w[d] = W[jj * EE + d];
  const float bj = bias[jj];

  float sc;
  {
    const int tkq = tok_ids[(size_t)b * SS];
    const float* er = emb + (size_t)tkq * EE;
    float em = bj;
#pragma unroll
    for (int d = 0; d < EE; ++d) em = fmaf(er[d], w[d], em);
    sc = start_t[jj] + em;
  }
  for (int t = 1; t < SS; ++t) {
    const int tkq = tok_ids[(size_t)b * SS + t];
    const float* er = emb + (size_t)tkq * EE;
    float em = bj;
#pragma unroll
    for (int d = 0; d < EE; ++d) em = fmaf(er[d], w[d], em);
    float best = -FLT_MAX; int bpi = 0;
#pragma unroll 1
    for (int i = 0; i < TT; ++i) {
      const float v = (__shfl(sc, i, 64) + trans[i * TT + jj]) + em;
      if (v > best) { best = v; bpi = i; }
    }
    if (lane < TT) bp[(size_t)(t - 1) * TT + lane] = (unsigned char)bpi;
    sc = best;
  }
  {
    float y = sc + end_t[jj];
    if (lane >= TT) y = -FLT_MAX;
    int idx = lane;
#pragma unroll
    for (int m = 32; m; m >>= 1) {
      const float oy = __shfl_xor(y, m, 64);
      const int oi = __shfl_xor(idx, m, 64);
      if (oy > y || (oy == y && oi < idx)) { y = oy; idx = oi; }
    }
    if (lane == 0) {
      int curtag = idx;
      out[(size_t)b * SS + (SS - 1)] = curtag;
      for (int t = SS - 2; t >= 0; --t) {
        curtag = bp[(size_t)t * TT + curtag];
        out[(size_t)b * SS + t] = curtag;
      }
    }
  }
}

extern "C" void kernel_launch(void* const* d_in, const int* in_sizes, int n_in,
                              void* d_out, int out_size, void* d_ws, size_t ws_size,
                              hipStream_t stream) {
  const int*   tok_ids = (const int*)d_in[0];
  const float* emb     = (const float*)d_in[1];
  const float* W       = (const float*)d_in[2];
  const float* bias    = (const float*)d_in[3];
  const float* start_t = (const float*)d_in[4];
  const float* end_t   = (const float*)d_in[5];
  const float* trans   = (const float*)d_in[6];
  int* out = (int*)d_out;
  unsigned char* bp = (unsigned char*)d_ws;

  k_one<<<BB, 1024, 0, stream>>>(tok_ids, emb, W, bias, start_t, end_t, trans,
                                 out, bp);
}